// Round 2
// baseline (4746.424 us; speedup 1.0000x reference)
//
#include <hip/hip_runtime.h>
#include <math.h>

// MultiScaleCodebook on MI355X — round 2: fix _resi_idx tie-break.
// Bit-exact float64 emulation of np.linspace/argmin gives qi(si=2)=1 (two
// 5/36 rational ties resolve by fp64 rounding: si=2 -> idx1, si=7 -> idx3).
// Chain (accu/pool/upsample/conv) in fp64 to match the np-float64 reference's
// argmin decisions; distance GEMM in fp32 with top-2 margin tracking + fp64
// re-scoring of near-ties (eps=0.01 >> fp32 GEMM error ~6e-4).
//
// Shapes: z[8,64,4,16,16], emb[16384,64], Wq[4,64,64,3,3,3], bq[4,64]
// Outputs (flat fp32): emb_st(524288), commit, ppl, avg_usage, usage(16384),
//                      ms_idx per scale (8,32,144,256,400,1152,2048,3200,5408,8192)

#define NCODES 16384
#define NELEM  524288   // 8*64*4*16*16
#define NSP    8192     // 8*4*16*16

// workspace byte offsets (total ~27.1 MB)
#define WS_ACCU   0ul
#define WS_HUP    4194304ul
#define WS_REST64 8388608ul
#define WS_PART   12582912ul
#define WS_ZCL    16777216ul
#define WS_ET     18874368ul
#define WS_ESQ    23068672ul
#define WS_TWT    23134208ul
#define WS_IDX    24903680ul
#define WS_CNT    24936448ul
#define WS_FLAGL  25001984ul
#define WS_FLAGC  25034752ul
#define WS_SSE    25034816ul
#define WS_ENT    25034824ul
#define WS_USED   25034832ul
#define WS_REST32 25034848ul

// ---------------------------------------------------------------- prep
__global__ __launch_bounds__(256) void prep_kernel(
    const float* __restrict__ z, const float* __restrict__ emb, const float* __restrict__ Wq,
    double* __restrict__ accu, float* __restrict__ zcl, float* __restrict__ et,
    float* __restrict__ esq, float* __restrict__ twt,
    int* __restrict__ counts, int* __restrict__ flagcnt,
    double* sse, double* ent, int* usedcnt)
{
  int i = blockIdx.x * 256 + threadIdx.x;
  if (i < NELEM) { accu[i] = 0.0; return; }
  i -= NELEM;
  if (i < NELEM) {  // z [B,C,T,H,W] -> zcl [B,T,H,W,C]
    int c = i & 63, w = (i >> 6) & 15, h = (i >> 10) & 15, t = (i >> 14) & 3, b = i >> 16;
    zcl[i] = z[(((b * 64 + c) * 4 + t) * 16 + h) * 16 + w];
    return;
  }
  i -= NELEM;
  if (i < NCODES * 64) {  // et[c][j] = emb[j][c]
    int j = i & (NCODES - 1); int c = i >> 14;
    et[i] = emb[j * 64 + c];
    return;
  }
  i -= NCODES * 64;
  if (i < NCODES) {  // e_sq fp32 (only used for candidate ranking; refine is fp64)
    float s = 0.f;
    for (int c = 0; c < 64; c++) { float v = emb[i * 64 + c]; s += v * v; }
    esq[i] = s; return;
  }
  i -= NCODES;
  if (i < 442368) {  // twt[qi][tap][ci][co] = Wq[qi][co][ci][tap]
    int qi = i / 110592; int r = i % 110592;
    int tap = r >> 12; int ci = (r >> 6) & 63; int co = r & 63;
    twt[i] = Wq[((qi * 64 + co) * 64 + ci) * 27 + tap];
    return;
  }
  i -= 442368;
  if (i < NCODES) { counts[i] = 0; return; }
  i -= NCODES;
  if (i < 16) {
    if (i < 10) flagcnt[i] = 0;
    else if (i == 10) *sse = 0.0;
    else if (i == 11) *ent = 0.0;
    else if (i == 12) *usedcnt = 0;
  }
}

// ---------------------------------------------------------------- pool (area)
__global__ __launch_bounds__(256) void pool_kernel(
    const float* __restrict__ zcl, const double* __restrict__ accu,
    double* __restrict__ rest64, float* __restrict__ rest32,
    int N, int tpn, int pn)
{
  int i = blockIdx.x * 256 + threadIdx.x;
  if (i >= N * 64) return;
  int n = i >> 6, c = i & 63;
  int ppn = pn * pn;
  int b = n / (tpn * ppn); int r = n % (tpn * ppn);
  int u = r / ppn; r %= ppn; int v = r / pn; int x = r % pn;
  int t0 = (u * 4) / tpn, t1 = ((u + 1) * 4 + tpn - 1) / tpn;
  int h0 = (v * 16) / pn, h1 = ((v + 1) * 16 + pn - 1) / pn;
  int w0 = (x * 16) / pn, w1 = ((x + 1) * 16 + pn - 1) / pn;
  double s = 0.0;
  for (int t = t0; t < t1; t++)
    for (int h = h0; h < h1; h++)
      for (int w = w0; w < w1; w++) {
        size_t off = (size_t)((((b * 4 + t) * 16 + h) * 16 + w) * 64 + c);
        s += (double)zcl[off] - accu[off];
      }
  // pool-matrix entries are fp32(1/n) used in fp64 arithmetic (matches ref)
  float wt = 1.f / (float)(t1 - t0), wh = 1.f / (float)(h1 - h0), ww = 1.f / (float)(w1 - w0);
  double rv = s * (double)wt * (double)wh * (double)ww;
  rest64[i] = rv;
  rest32[i] = (float)rv;
}

// ------------------------------------------------- argmin pass 1 (fp32 GEMM)
// grid (ceil(N/64), 32): 64 points x 512-code chunk per block; top-2 per row.
__global__ __launch_bounds__(256) void argmin_kernel(
    const float* __restrict__ rest32, const float* __restrict__ et,
    const float* __restrict__ esq, float4* __restrict__ part, int N)
{
  __shared__ __align__(16) float restT[64][64];  // [c][p]
  __shared__ __align__(16) float etile[64][64];  // [k][j]
  int tid = threadIdx.x;
  int pbase = blockIdx.x * 64;
  int ch = blockIdx.y;
#pragma unroll
  for (int it = 0; it < 4; it++) {
    int i2 = (tid + it * 256) * 4;
    int p = i2 >> 6, c = i2 & 63;
    float4 v = make_float4(0.f, 0.f, 0.f, 0.f);
    if (pbase + p < N) v = *(const float4*)&rest32[(size_t)(pbase + p) * 64 + c];
    restT[c + 0][p] = v.x; restT[c + 1][p] = v.y; restT[c + 2][p] = v.z; restT[c + 3][p] = v.w;
  }
  int tx = tid & 15, ty = tid >> 4;
  float m1[4], m2[4]; int i1[4];
#pragma unroll
  for (int r = 0; r < 4; r++) { m1[r] = 3.4e38f; m2[r] = 3.4e38f; i1[r] = 0x7fffffff; }
  for (int tile = 0; tile < 8; tile++) {
    int j0 = ch * 512 + tile * 64;
    __syncthreads();
#pragma unroll
    for (int it = 0; it < 4; it++) {
      int i2 = (tid + it * 256) * 4;
      int k = i2 >> 6, jj = i2 & 63;
      *(float4*)&etile[k][jj] = *(const float4*)&et[(size_t)k * NCODES + j0 + jj];
    }
    __syncthreads();
    float acc[4][4];
#pragma unroll
    for (int r = 0; r < 4; r++)
#pragma unroll
      for (int q = 0; q < 4; q++) acc[r][q] = 0.f;
#pragma unroll 8
    for (int k = 0; k < 64; k++) {
      float4 a = *(const float4*)&restT[k][ty * 4];
      float4 bb = *(const float4*)&etile[k][tx * 4];
      acc[0][0] += a.x * bb.x; acc[0][1] += a.x * bb.y; acc[0][2] += a.x * bb.z; acc[0][3] += a.x * bb.w;
      acc[1][0] += a.y * bb.x; acc[1][1] += a.y * bb.y; acc[1][2] += a.y * bb.z; acc[1][3] += a.y * bb.w;
      acc[2][0] += a.z * bb.x; acc[2][1] += a.z * bb.y; acc[2][2] += a.z * bb.z; acc[2][3] += a.z * bb.w;
      acc[3][0] += a.w * bb.x; acc[3][1] += a.w * bb.y; acc[3][2] += a.w * bb.z; acc[3][3] += a.w * bb.w;
    }
#pragma unroll
    for (int q = 0; q < 4; q++) {
      int j = j0 + tx * 4 + q;
      float es = esq[j];
#pragma unroll
      for (int r = 0; r < 4; r++) {
        float d = es - 2.f * acc[r][q];  // ||z||^2 shift is argmin-invariant
        if (d < m1[r]) { m2[r] = m1[r]; m1[r] = d; i1[r] = j; }
        else if (d < m2[r]) { m2[r] = d; }
      }
    }
  }
  // reduce top-2 across the 16 tx lanes (same wave)
#pragma unroll
  for (int off = 1; off < 16; off <<= 1) {
#pragma unroll
    for (int r = 0; r < 4; r++) {
      float o1 = __shfl_xor(m1[r], off);
      int   oi = __shfl_xor(i1[r], off);
      float o2 = __shfl_xor(m2[r], off);
      bool bwin = (o1 < m1[r]) || (o1 == m1[r] && oi < i1[r]);
      float nm2 = bwin ? fminf(m1[r], o2) : fminf(m2[r], o1);
      if (bwin) { m1[r] = o1; i1[r] = oi; }
      m2[r] = nm2;
    }
  }
  if (tx == 0) {
#pragma unroll
    for (int r = 0; r < 4; r++) {
      int n = pbase + ty * 4 + r;
      if (n < N) part[(size_t)ch * 8192 + n] = make_float4(m1[r], m2[r], __int_as_float(i1[r]), 0.f);
    }
  }
}

// ---------------------------------------------- argmin pass 2 (merge chunks)
__global__ __launch_bounds__(256) void reduce_kernel(
    const float4* __restrict__ part, int* __restrict__ idx_cur, float* __restrict__ out_idx,
    int* flagcnt, int* flaglist, int N)
{
  int n = blockIdx.x * 256 + threadIdx.x;
  if (n >= N) return;
  float m1 = 3.4e38f, m2 = 3.4e38f; int i1 = 0x7fffffff;
  for (int ch = 0; ch < 32; ch++) {
    float4 q = part[(size_t)ch * 8192 + n];
    float o1 = q.x, o2 = q.y; int oi = __float_as_int(q.z);
    bool bwin = (o1 < m1) || (o1 == m1 && oi < i1);
    float nm2 = bwin ? fminf(m1, o2) : fminf(m2, o1);
    if (bwin) { m1 = o1; i1 = oi; }
    m2 = nm2;
  }
  idx_cur[n] = i1;
  out_idx[n] = (float)i1;
  if (m2 - m1 < 0.01f) {  // near-tie: fp32 noise could differ from fp64 ref
    int pos = atomicAdd(flagcnt, 1);
    if (pos < 8192) flaglist[pos] = n;
  }
}

// ---------------------------------------------- argmin refine (fp64 rescan)
__global__ __launch_bounds__(256) void refine_kernel(
    const double* __restrict__ rest64, const float* __restrict__ emb,
    const int* __restrict__ flagcnt, const int* __restrict__ flaglist,
    int* __restrict__ idx_cur, float* __restrict__ out_idx)
{
  __shared__ double rl[64];
  __shared__ double bm[256];
  __shared__ int    bi[256];
  int cnt = *flagcnt; if (cnt > 8192) cnt = 8192;
  for (int f = blockIdx.x; f < cnt; f += gridDim.x) {
    int n = flaglist[f];
    __syncthreads();
    if (threadIdx.x < 64) rl[threadIdx.x] = rest64[(size_t)n * 64 + threadIdx.x];
    __syncthreads();
    double best = 1e300; int bidx = 0x7fffffff;
    for (int j = threadIdx.x; j < NCODES; j += 256) {
      double d = 0.0;
      for (int c = 0; c < 64; c++) { double df = rl[c] - (double)emb[(size_t)j * 64 + c]; d += df * df; }
      if (d < best) { best = d; bidx = j; }  // ascending j: keeps first min
    }
    bm[threadIdx.x] = best; bi[threadIdx.x] = bidx;
    __syncthreads();
    for (int s = 128; s > 0; s >>= 1) {
      if (threadIdx.x < s) {
        double ob = bm[threadIdx.x + s]; int oi = bi[threadIdx.x + s];
        if (ob < bm[threadIdx.x] || (ob == bm[threadIdx.x] && oi < bi[threadIdx.x])) {
          bm[threadIdx.x] = ob; bi[threadIdx.x] = oi;
        }
      }
      __syncthreads();
    }
    if (threadIdx.x == 0) { idx_cur[n] = bi[0]; out_idx[n] = (float)bi[0]; }
  }
}

// ------------------------------------------------------- trilinear upsample
__device__ inline void axis_map(int L, int outlen, int i, int* j0, int* j1, float* a0, float* a1) {
  if (L == 1) { *j0 = 0; *j1 = 0; *a0 = 1.f; *a1 = 0.f; return; }
  double scale = (double)L / (double)outlen;
  double src = (i + 0.5) * scale - 0.5;
  if (src < 0.0) src = 0.0;
  int i0 = (int)floor(src); if (i0 > L - 1) i0 = L - 1;
  int i1 = i0 + 1; if (i1 > L - 1) i1 = L - 1;
  double wv = src - (double)i0;
  if (i0 == i1) {
    // ref: M[i,i0] += 1-w then += w on a float32 array -> fp32 add of fp32 values
    float p = (float)(1.0 - wv), q = (float)wv;
    *a0 = p + q; *a1 = 0.f;
  } else { *a0 = (float)(1.0 - wv); *a1 = (float)wv; }
  *j0 = i0; *j1 = i1;
}

__global__ __launch_bounds__(256) void upsample_kernel(
    const float* __restrict__ emb, const int* __restrict__ idx_cur,
    double* __restrict__ hup, int tpn, int pn)
{
  int e = blockIdx.x * 256 + threadIdx.x;  // [b][t][h][w][c]
  int c = e & 63, w = (e >> 6) & 15, h = (e >> 10) & 15, t = (e >> 14) & 3, b = e >> 16;
  int t0, t1, h0, h1, w0, w1; float ta0, ta1, ha0, ha1, wa0, wa1;
  axis_map(tpn, 4, t, &t0, &t1, &ta0, &ta1);
  axis_map(pn, 16, h, &h0, &h1, &ha0, &ha1);
  axis_map(pn, 16, w, &w0, &w1, &wa0, &wa1);
  int ti[2] = {t0, t1}; float ta[2] = {ta0, ta1};
  int hi[2] = {h0, h1}; float ha[2] = {ha0, ha1};
  int wi[2] = {w0, w1}; float wa[2] = {wa0, wa1};
  double val = 0.0;
  for (int a = 0; a < 2; a++)
    for (int bb = 0; bb < 2; bb++)
      for (int cc = 0; cc < 2; cc++) {
        double wgt = (double)ta[a] * (double)ha[bb] * (double)wa[cc];
        if (wgt != 0.0) {
          int code = idx_cur[((b * tpn + ti[a]) * pn + hi[bb]) * pn + wi[cc]];
          val += wgt * (double)emb[(size_t)code * 64 + c];
        }
      }
  hup[e] = val;
}

// ------------------------------------------- conv3d + accu update + commit
// grid 256 = b*32 + t*8 + hq ; block: 16 w x 16 co-quads ; 2 h-rows/thread
__global__ __launch_bounds__(256) void conv_kernel(
    const double* __restrict__ hup, const float* __restrict__ twt, const float* __restrict__ bq,
    const float* __restrict__ zcl, double* __restrict__ accu, double* sse, int qi)
{
  __shared__ double hl[3][4][4][18];            // [tt][hh][cc][ww] halo tile, ci-chunk 4
  __shared__ __align__(16) double wl[27][4][64]; // [tap][cc][co]
  __shared__ double red[256];
  int bid = blockIdx.x;
  int b = bid >> 5, t = (bid >> 3) & 3, hq = bid & 7;
  int tid = threadIdx.x;
  int co4 = tid >> 4;  // 0..15 -> co = co4*4..+3
  int w = tid & 15;
  double acc[2][4];
  for (int k = 0; k < 2; k++) for (int q = 0; q < 4; q++) acc[k][q] = 0.0;
  for (int ci0 = 0; ci0 < 64; ci0 += 4) {
    __syncthreads();
    for (int i = tid; i < 864; i += 256) {
      int ww = i % 18; int r = i / 18; int cc = r & 3; r >>= 2; int hh = r & 3; int tt = r >> 2;
      int gt = t - 1 + tt, gh = hq * 2 - 1 + hh, gw = ww - 1;
      double v = 0.0;
      if (gt >= 0 && gt < 4 && gh >= 0 && gh < 16 && gw >= 0 && gw < 16)
        v = hup[(size_t)((((b * 4 + gt) * 16 + gh) * 16 + gw) * 64 + ci0 + cc)];
      hl[tt][hh][cc][ww] = v;
    }
    for (int i = tid; i < 6912; i += 256) {
      int co = i & 63; int r = i >> 6; int cc = r & 3; int tap = r >> 2;
      wl[tap][cc][co] = (double)twt[(size_t)(((qi * 27 + tap) * 64 + ci0 + cc) * 64 + co)];
    }
    __syncthreads();
    for (int tap = 0; tap < 27; tap++) {
      int dt = tap / 9, dh = (tap / 3) % 3, dw = tap % 3;
#pragma unroll
      for (int cc = 0; cc < 4; cc++) {
        double w0 = wl[tap][cc][co4 * 4 + 0];
        double w1 = wl[tap][cc][co4 * 4 + 1];
        double w2 = wl[tap][cc][co4 * 4 + 2];
        double w3 = wl[tap][cc][co4 * 4 + 3];
#pragma unroll
        for (int k = 0; k < 2; k++) {
          double hv = hl[dt][k + dh][cc][w + dw];
          acc[k][0] += hv * w0; acc[k][1] += hv * w1;
          acc[k][2] += hv * w2; acc[k][3] += hv * w3;
        }
      }
    }
  }
  double lsse = 0.0;
  for (int k = 0; k < 2; k++) {
    int gh = hq * 2 + k;
    for (int q = 0; q < 4; q++) {
      int co = co4 * 4 + q;
      size_t off = (size_t)((((b * 4 + t) * 16 + gh) * 16 + w) * 64 + co);
      double conv = acc[k][q] + (double)bq[qi * 64 + co];
      double hu = hup[off];
      double na = accu[off] + 0.5 * hu + 0.5 * conv;  // h*(1-q) + conv*q, q=0.5
      accu[off] = na;
      double df = na - (double)zcl[off];
      lsse += df * df;
    }
  }
  red[tid] = lsse;
  __syncthreads();
  for (int s = 128; s > 0; s >>= 1) { if (tid < s) red[tid] += red[tid + s]; __syncthreads(); }
  if (tid == 0) atomicAdd(sse, red[0]);
}

// ---------------------------------------------------------------- stats
__global__ __launch_bounds__(256) void bincount_kernel(const int* __restrict__ idx_cur, int* counts) {
  int i = blockIdx.x * 256 + threadIdx.x;
  if (i < NSP) atomicAdd(&counts[idx_cur[i]], 1);
}

__global__ __launch_bounds__(256) void stats_kernel(
    const int* __restrict__ counts, float* __restrict__ usage_out, double* ent, int* usedcnt)
{
  __shared__ double re[256];
  __shared__ int ru[256];
  int j = blockIdx.x * 256 + threadIdx.x;
  int cnt = counts[j];
  double p = (double)cnt / 8192.0;
  usage_out[j] = (float)p;
  re[threadIdx.x] = p * log(p + 1e-10);
  ru[threadIdx.x] = cnt > 0 ? 1 : 0;
  __syncthreads();
  for (int s = 128; s > 0; s >>= 1) {
    if (threadIdx.x < s) { re[threadIdx.x] += re[threadIdx.x + s]; ru[threadIdx.x] += ru[threadIdx.x + s]; }
    __syncthreads();
  }
  if (threadIdx.x == 0) { atomicAdd(ent, re[0]); atomicAdd(usedcnt, ru[0]); }
}

__global__ void final_kernel(const double* sse, const double* ent, const int* usedcnt, float* out) {
  if (threadIdx.x == 0) {
    out[NELEM]     = (float)(*sse * 0.25 / 524288.0 / 10.0);
    out[NELEM + 1] = (float)exp(-*ent);
    out[NELEM + 2] = (float)((double)*usedcnt / 16384.0);
  }
}

__global__ __launch_bounds__(256) void embst_kernel(const double* __restrict__ accu, float* __restrict__ out) {
  int e = blockIdx.x * 256 + threadIdx.x;  // out [B,C,T,H,W]
  int w = e & 15, h = (e >> 4) & 15, t = (e >> 8) & 3, c = (e >> 10) & 63, b = e >> 16;
  out[e] = (float)accu[(size_t)(((((b * 4 + t) * 16 + h) * 16 + w) * 64) + c)];
}

// ---------------------------------------------------------------- launch
extern "C" void kernel_launch(void* const* d_in, const int* in_sizes, int n_in,
                              void* d_out, int out_size, void* d_ws, size_t ws_size,
                              hipStream_t stream) {
  static const int T_PN_h[10] = {1, 1, 2, 2, 2, 4, 4, 4, 4, 4};
  static const int V_PN_h[10] = {1, 2, 3, 4, 5, 6, 8, 10, 13, 16};
  // qi from bit-exact fp64 emulation of np.linspace+argmin:
  // ticks={start, fl(step+start), fl(2step+start), stop}; rational ties at
  // si=2 (resolves to idx1, d1<d0 by 2ulp) and si=7 (idx3, d3<d2 by 1ulp).
  static const int QI_h[10]   = {0, 0, 1, 1, 1, 2, 2, 3, 3, 3};
  static const int NS_h[10]   = {8, 32, 144, 256, 400, 1152, 2048, 3200, 5408, 8192};
  static const int OB_h[10]   = {540675, 540683, 540715, 540859, 541115,
                                 541515, 542667, 544715, 547915, 553323};

  const float* z   = (const float*)d_in[0];
  const float* emb = (const float*)d_in[1];
  const float* Wq  = (const float*)d_in[2];
  const float* bq  = (const float*)d_in[3];
  float* out = (float*)d_out;
  char* ws = (char*)d_ws;

  double* accu    = (double*)(ws + WS_ACCU);
  double* hup     = (double*)(ws + WS_HUP);
  double* rest64  = (double*)(ws + WS_REST64);
  float4* part    = (float4*)(ws + WS_PART);
  float*  zcl     = (float*)(ws + WS_ZCL);
  float*  et      = (float*)(ws + WS_ET);
  float*  esq     = (float*)(ws + WS_ESQ);
  float*  twt     = (float*)(ws + WS_TWT);
  int*    idx_cur = (int*)(ws + WS_IDX);
  int*    counts  = (int*)(ws + WS_CNT);
  int*    flaglist= (int*)(ws + WS_FLAGL);
  int*    flagcnt = (int*)(ws + WS_FLAGC);
  double* sse     = (double*)(ws + WS_SSE);
  double* ent     = (double*)(ws + WS_ENT);
  int*    usedcnt = (int*)(ws + WS_USED);
  float*  rest32  = (float*)(ws + WS_REST32);

  prep_kernel<<<10049, 256, 0, stream>>>(z, emb, Wq, accu, zcl, et, esq, twt,
                                         counts, flagcnt, sse, ent, usedcnt);

  for (int si = 0; si < 10; si++) {
    int tpn = T_PN_h[si], pn = V_PN_h[si], N = NS_h[si];
    pool_kernel<<<(N * 64 + 255) / 256, 256, 0, stream>>>(zcl, accu, rest64, rest32, N, tpn, pn);
    dim3 ag((N + 63) / 64, 32);
    argmin_kernel<<<ag, 256, 0, stream>>>(rest32, et, esq, part, N);
    reduce_kernel<<<(N + 255) / 256, 256, 0, stream>>>(part, idx_cur, out + OB_h[si],
                                                       flagcnt + si, flaglist, N);
    refine_kernel<<<64, 256, 0, stream>>>(rest64, emb, flagcnt + si, flaglist,
                                          idx_cur, out + OB_h[si]);
    upsample_kernel<<<NELEM / 256, 256, 0, stream>>>(emb, idx_cur, hup, tpn, pn);
    conv_kernel<<<256, 256, 0, stream>>>(hup, twt, bq, zcl, accu, sse, QI_h[si]);
  }

  bincount_kernel<<<32, 256, 0, stream>>>(idx_cur, counts);
  stats_kernel<<<64, 256, 0, stream>>>(counts, out + 524291, ent, usedcnt);
  final_kernel<<<1, 64, 0, stream>>>(sse, ent, usedcnt, out);
  embst_kernel<<<NELEM / 256, 256, 0, stream>>>(accu, out);
}